// Round 4
// baseline (165.763 us; speedup 1.0000x reference)
//
#include <hip/hip_runtime.h>
#include <hip/hip_bf16.h>

#define N_NODES 50000
#define N_EDGES 800000

__device__ __forceinline__ float leaky(float l) { return (l >= 0.0f) ? l : 0.2f * l; }
__device__ __forceinline__ float blo(unsigned u) { return __uint_as_float(u << 16); }
__device__ __forceinline__ float bhi(unsigned u) { return __uint_as_float(u & 0xffff0000u); }

// ---------------- k1: fused linear + attention scores + in-degree hist ----------
// h[n][o] = sum_k concat(x,state)[n][k] * W[o][k];  o = h*16+d
__global__ void k1_linear(const float* __restrict__ x, const float* __restrict__ state,
                          const float* __restrict__ W, const float* __restrict__ a_src,
                          const float* __restrict__ a_dst, const int* __restrict__ ei,
                          unsigned short* __restrict__ hf2, float* __restrict__ s_src4,
                          float* __restrict__ s_dst4, int* __restrict__ deg) {
    __shared__ float wlds[64 * 132];   // pad 132: quad-stride -> ~2-way bank, free
    __shared__ float asrc_l[64];
    __shared__ float adst_l[64];
    __shared__ float inrow[4][128];

    int tid = threadIdx.x;             // 256 threads = 4 waves

    // fused in-degree histogram (independent of linear pass; hides behind it)
    int gtid = blockIdx.x * 256 + tid;
    if (gtid * 4 < N_EDGES) {
        int4 dv = *(const int4*)(ei + N_EDGES + gtid * 4);
        atomicAdd(&deg[dv.x], 1);
        atomicAdd(&deg[dv.y], 1);
        atomicAdd(&deg[dv.z], 1);
        atomicAdd(&deg[dv.w], 1);
    }

    const float4* W4 = (const float4*)W;   // [64][32] quads
    for (int i = tid; i < 2048; i += 256) {
        int r = i >> 5, c = i & 31;
        *(float4*)&wlds[r * 132 + c * 4] = W4[i];
    }
    if (tid < 64) { asrc_l[tid] = a_src[tid]; adst_l[tid] = a_dst[tid]; }
    __syncthreads();

    int wave = tid >> 6;
    int lane = tid & 63;               // output dim o
    int h = lane >> 4, d = lane & 15;
    float asv = asrc_l[lane];
    float adv = adst_l[lane];
    const float* wr = &wlds[lane * 132];

    for (int n = blockIdx.x * 4 + wave; n < N_NODES; n += gridDim.x * 4) {
        inrow[wave][lane]      = x[(long)n * 64 + lane];
        inrow[wave][64 + lane] = state[(long)n * 64 + lane];
        float acc = 0.0f;
#pragma unroll
        for (int kq = 0; kq < 32; ++kq) {
            float4 wv = *(const float4*)&wr[kq * 4];
            float4 iv = *(const float4*)&inrow[wave][kq * 4];
            acc = fmaf(iv.x, wv.x, acc);
            acc = fmaf(iv.y, wv.y, acc);
            acc = fmaf(iv.z, wv.z, acc);
            acc = fmaf(iv.w, wv.w, acc);
        }
        __hip_bfloat16 hb = __float2bfloat16(acc);
        hf2[(long)n * 64 + lane] = *(unsigned short*)&hb;

        float vs = acc * asv, vd = acc * adv;
#pragma unroll
        for (int off = 8; off; off >>= 1) {
            vs += __shfl_xor(vs, off);
            vd += __shfl_xor(vd, off);
        }
        if (d == 0) {
            s_src4[(long)n * 4 + h] = vs;
            s_dst4[(long)n * 4 + h] = vd;
        }
    }
}

// ---------------- k_assign: disjoint CSR ranges via block-scan + 1 atomic/block ----
__global__ void k_assign(const int* __restrict__ deg, int* __restrict__ off,
                         int* __restrict__ pos, int* __restrict__ ctr) {
    __shared__ int wsum[4];
    __shared__ int base_sh;
    int tid = threadIdx.x, lane = tid & 63, wid = tid >> 6;
    int i = blockIdx.x * 256 + tid;
    int v = (i < N_NODES) ? deg[i] : 0;
    int inc = v;
#pragma unroll
    for (int s = 1; s < 64; s <<= 1) {
        int t = __shfl_up(inc, s);
        if (lane >= s) inc += t;
    }
    if (lane == 63) wsum[wid] = inc;
    __syncthreads();
    if (tid == 0) {
        int s = 0;
#pragma unroll
        for (int w = 0; w < 4; ++w) { int t = wsum[w]; wsum[w] = s; s += t; }
        base_sh = atomicAdd(ctr, s);
    }
    __syncthreads();
    int excl = base_sh + wsum[wid] + inc - v;
    if (i < N_NODES) { off[i] = excl; pos[i] = excl; }
}

// ---------------- k_scatter: bucket edges by dst (4B payload only) --------------
__global__ void k_scatter(const int* __restrict__ ei, int* __restrict__ pos,
                          int* __restrict__ csr) {
    int t = blockIdx.x * 256 + threadIdx.x;
    int e0 = t * 2;
    if (e0 >= N_EDGES) return;
    int2 sv = *(const int2*)(ei + e0);
    int2 dv = *(const int2*)(ei + N_EDGES + e0);
    int s0 = atomicAdd(&pos[dv.x], 1);
    csr[s0] = sv.x;
    int s1 = atomicAdd(&pos[dv.y], 1);
    csr[s1] = sv.y;
}

// ---------------- k_agg: per-dst softmax + aggregation (1 wave/node, 8 edge slots)
__global__ void k_agg(const int* __restrict__ off, const int* __restrict__ deg,
                      const int* __restrict__ csr, const float* __restrict__ s_src4,
                      const float* __restrict__ s_dst4,
                      const unsigned short* __restrict__ h2, float* __restrict__ out) {
    int wave = threadIdx.x >> 6, lane = threadIdx.x & 63;
    int n = blockIdx.x * 4 + wave;
    if (n >= N_NODES) return;
    int q = lane >> 3, d = lane & 7, hh = d >> 1;   // slot q, dim-octet d, head hh
    int b = off[n], nE = deg[n];
    float sdl = s_dst4[(long)n * 4 + (lane & 3)];
    float sdh = s_dst4[(long)n * 4 + hh];

    // pass 1: per-head max (16 edges x 4 heads per 64-lane step)
    float m = -INFINITY;
    int nE4 = nE * 4;
    for (int j = lane; j < nE4; j += 64) {
        int sE = csr[b + (j >> 2)];
        float ss = s_src4[(long)sE * 4 + (lane & 3)];
        m = fmaxf(m, leaky(ss + sdl));
    }
    m = fmaxf(m, __shfl_xor(m, 4));
    m = fmaxf(m, __shfl_xor(m, 8));
    m = fmaxf(m, __shfl_xor(m, 16));
    m = fmaxf(m, __shfl_xor(m, 32));
    float mh = __shfl(m, hh);          // max for this lane's head

    // pass 2: 8 edges in flight; lane d owns dims 8d..8d+7 (head hh)
    float den = 0.0f;
    float a0 = 0, a1 = 0, a2 = 0, a3 = 0, a4 = 0, a5 = 0, a6 = 0, a7 = 0;
    for (int c = 0; c < nE; c += 64) {
        int jn = min(64, nE - c);
        int svl = (lane < jn) ? csr[b + c + lane] : 0;
        for (int j = 0; j < jn; j += 8) {
            int myj = j + q;
            int s = __shfl(svl, myj);  // uniform shfl (outside divergence)
            if (myj < jn) {
                float ss = s_src4[(long)s * 4 + hh];
                float ex = __expf(leaky(ss + sdh) - mh);
                if (!(d & 1)) den += ex;           // count each (edge,head) once
                uint4 hv = *(const uint4*)(h2 + (long)s * 64 + 8 * d);
                a0 = fmaf(ex, blo(hv.x), a0);
                a1 = fmaf(ex, bhi(hv.x), a1);
                a2 = fmaf(ex, blo(hv.y), a2);
                a3 = fmaf(ex, bhi(hv.y), a3);
                a4 = fmaf(ex, blo(hv.z), a4);
                a5 = fmaf(ex, bhi(hv.z), a5);
                a6 = fmaf(ex, blo(hv.w), a6);
                a7 = fmaf(ex, bhi(hv.w), a7);
            }
        }
    }
#pragma unroll
    for (int o2 = 8; o2 < 64; o2 <<= 1) {          // reduce across the 8 slots
        den += __shfl_xor(den, o2);
        a0 += __shfl_xor(a0, o2);
        a1 += __shfl_xor(a1, o2);
        a2 += __shfl_xor(a2, o2);
        a3 += __shfl_xor(a3, o2);
        a4 += __shfl_xor(a4, o2);
        a5 += __shfl_xor(a5, o2);
        a6 += __shfl_xor(a6, o2);
        a7 += __shfl_xor(a7, o2);
    }
    den += __shfl_xor(den, 1);                     // share even-lane den to odd

    if (q == 0) {
        uint4 hr = *(const uint4*)(h2 + (long)n * 64 + 8 * d);
        float inv = 1.0f / (den + 1e-12f);
        float o[8];
        o[0] = a0 * inv + blo(hr.x);
        o[1] = a1 * inv + bhi(hr.x);
        o[2] = a2 * inv + blo(hr.y);
        o[3] = a3 * inv + bhi(hr.y);
        o[4] = a4 * inv + blo(hr.z);
        o[5] = a5 * inv + bhi(hr.z);
        o[6] = a6 * inv + blo(hr.w);
        o[7] = a7 * inv + bhi(hr.w);
#pragma unroll
        for (int k = 0; k < 8; ++k) o[k] = (o[k] > 0.0f) ? o[k] : expm1f(o[k]);
        float4 w0 = {o[0], o[1], o[2], o[3]};
        float4 w1 = {o[4], o[5], o[6], o[7]};
        *(float4*)&out[(long)n * 64 + 8 * d]     = w0;
        *(float4*)&out[(long)n * 64 + 8 * d + 4] = w1;
    }
}

extern "C" void kernel_launch(void* const* d_in, const int* in_sizes, int n_in,
                              void* d_out, int out_size, void* d_ws, size_t ws_size,
                              hipStream_t stream) {
    const float* x      = (const float*)d_in[0];
    const float* state  = (const float*)d_in[1];
    const int*   ei     = (const int*)d_in[2];     // [2, E]
    // d_in[3] = edge_weight (ignored)
    const float* W      = (const float*)d_in[4];   // [64,128]
    const float* a_src  = (const float*)d_in[5];
    const float* a_dst  = (const float*)d_in[6];

    float* out = (float*)d_out;

    // ws layout: hf2 [N*64] u16 | s_src4 [N*4] f32 | s_dst4 [N*4] | deg [N] |
    //            off [N] | pos [N] | ctr [4] | csr [E]
    unsigned short* hf2 = (unsigned short*)d_ws;
    float* s_src4 = (float*)(hf2 + (long)N_NODES * 64);
    float* s_dst4 = s_src4 + (long)N_NODES * 4;
    int*   deg    = (int*)(s_dst4 + (long)N_NODES * 4);
    int*   off    = deg + N_NODES;
    int*   pos    = off + N_NODES;
    int*   ctr    = pos + N_NODES;
    int*   csr    = ctr + 4;

    hipMemsetAsync(deg, 0, N_NODES * sizeof(int), stream);
    hipMemsetAsync(ctr, 0, sizeof(int), stream);
    k1_linear<<<2048, 256, 0, stream>>>(x, state, W, a_src, a_dst, ei,
                                        hf2, s_src4, s_dst4, deg);
    k_assign<<<(N_NODES + 255) / 256, 256, 0, stream>>>(deg, off, pos, ctr);
    k_scatter<<<(N_EDGES / 2 + 255) / 256, 256, 0, stream>>>(ei, pos, csr);
    k_agg<<<(N_NODES + 3) / 4, 256, 0, stream>>>(off, deg, csr, s_src4, s_dst4, hf2, out);
}